// Round 5
// baseline (68.095 us; speedup 1.0000x reference)
//
#include <hip/hip_runtime.h>

#define E_N 8192
#define V_N 2048
#define F_N 2048
#define B_N 8
#define H_N 128
#define DEC_N 128
#define EDGE_N 2
#define META_N 4
#define IN_DIM 134
#define MEMH 256
#define MEMAGG 128
#define AGGH 128

typedef __attribute__((ext_vector_type(8))) short short8;
typedef __attribute__((ext_vector_type(4))) float f32x4;

__device__ inline unsigned short f2bf(float x) {
    unsigned u = __float_as_uint(x);
    unsigned r = (u + 0x7FFFu + ((u >> 16) & 1u)) >> 16;
    return (unsigned short)r;
}

__device__ inline short8 pack8(float4 u0, float4 u1) {
    short8 s;
    s[0] = (short)f2bf(u0.x); s[1] = (short)f2bf(u0.y);
    s[2] = (short)f2bf(u0.z); s[3] = (short)f2bf(u0.w);
    s[4] = (short)f2bf(u1.x); s[5] = (short)f2bf(u1.y);
    s[6] = (short)f2bf(u1.z); s[7] = (short)f2bf(u1.w);
    return s;
}

__device__ inline int probe4(float4 v, int c, int hit) {
    if (hit < 0) {
        if      (v.x != 0.f) hit = c;
        else if (v.y != 0.f) hit = c + 1;
        else if (v.z != 0.f) hit = c + 2;
        else if (v.w != 0.f) hit = c + 3;
    }
    return hit;
}

// ---------------------------------------------------------------------------
struct RDesc { const float* src; unsigned short* dst; int K; int N; int Kp; };
struct SetupArgs { RDesc d[8]; float* nszero; const float* bvm; int* bov; };

__global__ __launch_bounds__(256) void k_setup(SetupArgs p) {
    if (blockIdx.y == 8) {
        if (blockIdx.x < 8) {
            int v = blockIdx.x * 256 + threadIdx.x;
            float s = 0.f;
#pragma unroll
            for (int b = 0; b < B_N; ++b) s += p.bvm[v * B_N + b] * (float)b;
            p.bov[v] = (int)(s + 0.5f);
        }
        return;
    }
    int gid = (int)((blockIdx.y * 160 + blockIdx.x) * 256 + threadIdx.x);
    const int NZ4 = (V_N + F_N) * MEMAGG / 4;
    if (gid < NZ4) ((float4*)p.nszero)[gid] = (float4){0.f, 0.f, 0.f, 0.f};

    RDesc d = p.d[blockIdx.y];
    int i = blockIdx.x * 256 + threadIdx.x;
    int total = d.Kp * d.N;
    if (i >= total) return;
    int elem = i & 7;
    int lane = (i >> 3) & 63;
    int f    = i >> 9;
    int c16n = d.N >> 4;
    int c16 = f % c16n, kc = f / c16n;
    int k = kc * 32 + (lane >> 4) * 8 + elem;
    int c = c16 * 16 + (lane & 15);
    float v = (k < d.K) ? d.src[(size_t)k * d.N + c] : 0.f;
    d.dst[i] = f2bf(v);
}

// ---------------------------------------------------------------------------
// Variable-mask scan only: var_idx + emask + gfeat. One wave scans 4 rows,
// round-0 (first half-row) prefetched for all 4 rows.
__global__ __launch_bounds__(256) void k_scanv(const float* __restrict__ vmt,
                                               int* __restrict__ vidx,
                                               const int* __restrict__ bov,
                                               const int* __restrict__ active,
                                               const float* __restrict__ meta,
                                               float* __restrict__ emask,
                                               float* __restrict__ gfeat) {
    int wave = threadIdx.x >> 6, lane = threadIdx.x & 63;
    int e0 = blockIdx.x * 16 + wave * 4;
    const float4* rp[4];
    float4 h[4][4];
#pragma unroll
    for (int r = 0; r < 4; ++r) {
        rp[r] = (const float4*)(vmt + (size_t)(e0 + r) * V_N);
#pragma unroll
        for (int j = 0; j < 4; ++j) h[r][j] = rp[r][j * 64 + lane];
    }
#pragma unroll
    for (int r = 0; r < 4; ++r) {
        int hit = -1;
#pragma unroll
        for (int j = 0; j < 4; ++j) hit = probe4(h[r][j], (j * 64 + lane) * 4, hit);
        unsigned long long bm = __ballot(hit >= 0);
        if (!bm) {
#pragma unroll
            for (int j = 0; j < 4; ++j) {
                float4 v = rp[r][256 + j * 64 + lane];
                hit = probe4(v, 1024 + (j * 64 + lane) * 4, hit);
            }
            bm = __ballot(hit >= 0);
        }
        int pos = __shfl(hit, __ffsll((long long)bm) - 1);
        if (lane == 0) {
            vidx[e0 + r] = pos;
            int b = bov[pos];
            emask[e0 + r] = (float)active[b];
            ((float4*)gfeat)[e0 + r] = ((const float4*)meta)[b];
        }
    }
}

// ---------------------------------------------------------------------------
struct F1Args {
    const float* dec[2];
    const float* ef;
    const float* gfeat;
    const float* fmt;                // fmask_t for the inline fun-branch scan
    const unsigned short* wpack[2];
    const float* b1[2];
    const float* b2[2];
    int* idx[2];
    float* h2[2];
    float* ns[2];
};

__global__ __launch_bounds__(256) void k_fused1(F1Args A) {
    int br = blockIdx.y;
    const float* dec = A.dec[br];
    const unsigned short* W1f = A.wpack[br];
    const unsigned short* W2f = A.wpack[br] + 160 * 256;
    const float* b1 = A.b1[br];
    const float* b2 = A.b2[br];
    float* h2o = A.h2[br];
    float* ns  = A.ns[br];

    int tid = threadIdx.x;
    int wave = tid >> 6, lane = tid & 63;
    int lrow = lane & 15, lgrp = lane >> 4;
    int e0 = blockIdx.x * 16;

    __shared__ unsigned short h1s[16 * 256];  // 8 KB
    __shared__ int idxs[16];

    if (br == 0) {
        if (tid < 16) idxs[tid] = A.idx[0][e0 + tid];
    } else {
        // inline scan of this block's 16 fmask_t rows (4 rows per wave)
        int ew = e0 + wave * 4;
        const float4* rp[4];
        float4 h[4][4];
#pragma unroll
        for (int r = 0; r < 4; ++r) {
            rp[r] = (const float4*)(A.fmt + (size_t)(ew + r) * F_N);
#pragma unroll
            for (int j = 0; j < 4; ++j) h[r][j] = rp[r][j * 64 + lane];
        }
#pragma unroll
        for (int r = 0; r < 4; ++r) {
            int hit = -1;
#pragma unroll
            for (int j = 0; j < 4; ++j) hit = probe4(h[r][j], (j * 64 + lane) * 4, hit);
            unsigned long long bm = __ballot(hit >= 0);
            if (!bm) {
#pragma unroll
                for (int j = 0; j < 4; ++j) {
                    float4 v = rp[r][256 + j * 64 + lane];
                    hit = probe4(v, 1024 + (j * 64 + lane) * 4, hit);
                }
                bm = __ballot(hit >= 0);
            }
            int pos = __shfl(hit, __ffsll((long long)bm) - 1);
            if (lane == 0) {
                idxs[wave * 4 + r] = pos;
                A.idx[1][ew + r] = pos;
            }
        }
    }

    // ---- GEMM1: (16 x 256) = dvs(16 x 160pad) @ W1; wave owns 64 cols
    int n0 = wave * 64;
    f32x4 acc1[4];
#pragma unroll
    for (int nt = 0; nt < 4; ++nt) {
        float bv = b1[n0 + nt * 16 + lrow];
        acc1[nt] = (f32x4){bv, bv, bv, bv};
    }
    const float4* dec4 = (const float4*)dec;
    int r = e0 + lrow;
#pragma unroll
    for (int kc = 0; kc < 5; ++kc) {
        short8 a;
        if (kc < 4) {
            float4 u0 = dec4[(size_t)r * 32 + kc * 8 + lgrp * 2];
            float4 u1 = dec4[(size_t)r * 32 + kc * 8 + lgrp * 2 + 1];
            a = pack8(u0, u1);
        } else {
            short8 z = (short8)0;
            if (lgrp == 0) {
                z[0] = (short)f2bf(A.ef[r * 2]);
                z[1] = (short)f2bf(A.ef[r * 2 + 1]);
                z[2] = (short)f2bf(A.gfeat[r * 4]);
                z[3] = (short)f2bf(A.gfeat[r * 4 + 1]);
                z[4] = (short)f2bf(A.gfeat[r * 4 + 2]);
                z[5] = (short)f2bf(A.gfeat[r * 4 + 3]);
            }
            a = z;
        }
#pragma unroll
        for (int nt = 0; nt < 4; ++nt) {
            short8 b = *(const short8*)(W1f + ((size_t)(kc * 16 + (n0 >> 4) + nt) * 64 + lane) * 8);
            acc1[nt] = __builtin_amdgcn_mfma_f32_16x16x32_bf16(a, b, acc1[nt], 0, 0, 0);
        }
    }
    // relu -> LDS (bf16, XOR-swizzled)
#pragma unroll
    for (int nt = 0; nt < 4; ++nt)
#pragma unroll
        for (int j = 0; j < 4; ++j) {
            int row = lgrp * 4 + j;
            int col = n0 + nt * 16 + lrow;
            h1s[row * 256 + (col ^ ((row & 7) << 3))] = f2bf(fmaxf(acc1[nt][j], 0.f));
        }
    __syncthreads();

    // ---- GEMM2: (16 x 128) = h1 @ W2; wave owns 32 cols
    int c0 = wave * 32;
    f32x4 acc2[2];
#pragma unroll
    for (int nt = 0; nt < 2; ++nt) {
        float bv = b2[c0 + nt * 16 + lrow];
        acc2[nt] = (f32x4){bv, bv, bv, bv};
    }
#pragma unroll
    for (int kc = 0; kc < 8; ++kc) {
        int kb = kc * 32 + lgrp * 8;
        short8 a2 = *(const short8*)(h1s + lrow * 256 + (kb ^ ((lrow & 7) << 3)));
#pragma unroll
        for (int nt = 0; nt < 2; ++nt) {
            short8 b = *(const short8*)(W2f + ((size_t)(kc * 8 + (c0 >> 4) + nt) * 64 + lane) * 8);
            acc2[nt] = __builtin_amdgcn_mfma_f32_16x16x32_bf16(a2, b, acc2[nt], 0, 0, 0);
        }
    }
    // h2 -> global; scatter-add into node sums (indices via LDS)
#pragma unroll
    for (int j = 0; j < 4; ++j) {
        int row = e0 + lgrp * 4 + j;
        int node = idxs[lgrp * 4 + j];
#pragma unroll
        for (int nt = 0; nt < 2; ++nt) {
            int col = c0 + nt * 16 + lrow;
            float v = acc2[nt][j];
            h2o[(size_t)row * 128 + col] = v;
            atomicAdd(ns + (size_t)node * 128 + col, v);
        }
    }
}

// ---------------------------------------------------------------------------
struct F2Args {
    const unsigned short* wpack[2];
    const float* c1[2];
    const float* c2[2];
    const float* h2[2];
    const float* ns[2];
    const int* idx[2];
    const float* ef;
    const float* emask;
    const float* oldst[2];
    float* outst[2];
};

__global__ __launch_bounds__(256) void k_fused2(F2Args A) {
    int br = blockIdx.y;
    const unsigned short* A1f = A.wpack[br] + 160 * 256 + 256 * 128;
    const unsigned short* A2f = A1f + 160 * 128;
    const float* c1 = A.c1[br];
    const float* c2 = A.c2[br];
    const float* h2 = A.h2[br];
    const float* ns = A.ns[br];
    const int* idx = A.idx[br];
    const float* oldst = A.oldst[br];
    float* outst = A.outst[br];

    int tid = threadIdx.x;
    int wave = tid >> 6, lane = tid & 63;
    int lrow = lane & 15, lgrp = lane >> 4;
    int e0 = blockIdx.x * 16;

    __shared__ unsigned short as_[16 * 128];  // 4 KB

    int n0 = wave * 32;
    f32x4 accp[2];
#pragma unroll
    for (int nt = 0; nt < 2; ++nt) {
        float bv = c1[n0 + nt * 16 + lrow];
        accp[nt] = (f32x4){bv, bv, bv, bv};
    }
    const float4* ns4 = (const float4*)ns;
    const float4* h24 = (const float4*)h2;
    int r = e0 + lrow;
    int node = idx[r];
#pragma unroll
    for (int kc = 0; kc < 5; ++kc) {
        short8 a;
        if (kc < 4) {
            float4 u0 = ns4[(size_t)node * 32 + kc * 8 + lgrp * 2];
            float4 u1 = ns4[(size_t)node * 32 + kc * 8 + lgrp * 2 + 1];
            float4 v0 = h24[(size_t)r * 32 + kc * 8 + lgrp * 2];
            float4 v1 = h24[(size_t)r * 32 + kc * 8 + lgrp * 2 + 1];
            float4 d0 = {u0.x - v0.x, u0.y - v0.y, u0.z - v0.z, u0.w - v0.w};
            float4 d1 = {u1.x - v1.x, u1.y - v1.y, u1.z - v1.z, u1.w - v1.w};
            a = pack8(d0, d1);
        } else {
            short8 z = (short8)0;
            if (lgrp == 0) {
                z[0] = (short)f2bf(A.ef[r * 2]);
                z[1] = (short)f2bf(A.ef[r * 2 + 1]);
            }
            a = z;
        }
#pragma unroll
        for (int nt = 0; nt < 2; ++nt) {
            short8 b = *(const short8*)(A1f + ((size_t)(kc * 8 + (n0 >> 4) + nt) * 64 + lane) * 8);
            accp[nt] = __builtin_amdgcn_mfma_f32_16x16x32_bf16(a, b, accp[nt], 0, 0, 0);
        }
    }
#pragma unroll
    for (int nt = 0; nt < 2; ++nt)
#pragma unroll
        for (int j = 0; j < 4; ++j) {
            int row = lgrp * 4 + j;
            int col = n0 + nt * 16 + lrow;
            as_[row * 128 + (col ^ ((row & 7) << 3))] = f2bf(fmaxf(accp[nt][j], 0.f));
        }
    __syncthreads();

    f32x4 acco[2];
#pragma unroll
    for (int nt = 0; nt < 2; ++nt) {
        float bv = c2[n0 + nt * 16 + lrow];
        acco[nt] = (f32x4){bv, bv, bv, bv};
    }
#pragma unroll
    for (int kc = 0; kc < 4; ++kc) {
        int kb = kc * 32 + lgrp * 8;
        short8 a2 = *(const short8*)(as_ + lrow * 128 + (kb ^ ((lrow & 7) << 3)));
#pragma unroll
        for (int nt = 0; nt < 2; ++nt) {
            short8 b = *(const short8*)(A2f + ((size_t)(kc * 8 + (n0 >> 4) + nt) * 64 + lane) * 8);
            acco[nt] = __builtin_amdgcn_mfma_f32_16x16x32_bf16(a2, b, acco[nt], 0, 0, 0);
        }
    }
#pragma unroll
    for (int j = 0; j < 4; ++j) {
        int row = e0 + lgrp * 4 + j;
        float m = A.emask[row];
#pragma unroll
        for (int nt = 0; nt < 2; ++nt) {
            int col = n0 + nt * 16 + lrow;
            float old = oldst[(size_t)row * 128 + col];
            outst[(size_t)row * 128 + col] = m * acco[nt][j] + (1.f - m) * old;
        }
    }
}

// ---------------------------------------------------------------------------
extern "C" void kernel_launch(void* const* d_in, const int* in_sizes, int n_in,
                              void* d_out, int out_size, void* d_ws, size_t ws_size,
                              hipStream_t stream) {
    const float* variable_state = (const float*)d_in[0];
    const float* function_state = (const float*)d_in[1];
    const float* dec_v          = (const float*)d_in[2];
    const float* dec_f          = (const float*)d_in[3];
    const float* ef             = (const float*)d_in[4];
    const float* meta           = (const float*)d_in[5];
    const int*   active         = (const int*)d_in[6];
    const float* vmask_t        = (const float*)d_in[8];
    const float* fmask_t        = (const float*)d_in[10];
    const float* bvm            = (const float*)d_in[11];
    const float* vM1w = (const float*)d_in[12]; const float* vM1b = (const float*)d_in[13];
    const float* vM2w = (const float*)d_in[14]; const float* vM2b = (const float*)d_in[15];
    const float* vA1w = (const float*)d_in[16]; const float* vA1b = (const float*)d_in[17];
    const float* vA2w = (const float*)d_in[18]; const float* vA2b = (const float*)d_in[19];
    const float* fM1w = (const float*)d_in[20]; const float* fM1b = (const float*)d_in[21];
    const float* fM2w = (const float*)d_in[22]; const float* fM2b = (const float*)d_in[23];
    const float* fA1w = (const float*)d_in[24]; const float* fA1b = (const float*)d_in[25];
    const float* fA2w = (const float*)d_in[26]; const float* fA2b = (const float*)d_in[27];

    float* out_vs = (float*)d_out;
    float* out_fs = (float*)d_out + (size_t)E_N * H_N;

    int*   var_idx = (int*)d_ws;
    int*   fun_idx = var_idx + E_N;
    int*   bov     = fun_idx + E_N;
    float* emask   = (float*)(bov + V_N);
    float* gfeat   = emask + E_N;
    float* hv2     = gfeat + (size_t)E_N * 4;
    float* hf2     = hv2 + (size_t)E_N * MEMAGG;
    float* nsv     = hf2 + (size_t)E_N * MEMAGG;
    float* nsf     = nsv + (size_t)V_N * MEMAGG;
    unsigned short* wpack = (unsigned short*)(nsf + (size_t)F_N * MEMAGG);
    const int PBR = 160 * 256 + 256 * 128 + 160 * 128 + 128 * 128;
    unsigned short* wpv = wpack;
    unsigned short* wpf = wpack + PBR;

    SetupArgs sp;
    sp.d[0] = {vM1w, wpv,                          IN_DIM, MEMH,   160};
    sp.d[1] = {vM2w, wpv + 160 * 256,              MEMH,   MEMAGG, 256};
    sp.d[2] = {vA1w, wpv + 160 * 256 + 256 * 128,  130,    AGGH,   160};
    sp.d[3] = {vA2w, wpv + 160 * 256 + 256 * 128 + 160 * 128, 128, H_N, 128};
    sp.d[4] = {fM1w, wpf,                          IN_DIM, MEMH,   160};
    sp.d[5] = {fM2w, wpf + 160 * 256,              MEMH,   MEMAGG, 256};
    sp.d[6] = {fA1w, wpf + 160 * 256 + 256 * 128,  130,    AGGH,   160};
    sp.d[7] = {fA2w, wpf + 160 * 256 + 256 * 128 + 160 * 128, 128, H_N, 128};
    sp.nszero = nsv;
    sp.bvm = bvm;
    sp.bov = bov;
    k_setup<<<dim3(160, 9), 256, 0, stream>>>(sp);

    k_scanv<<<E_N / 16, 256, 0, stream>>>(vmask_t, var_idx, bov, active, meta,
                                          emask, gfeat);

    F1Args f1;
    f1.dec[0] = dec_v;  f1.dec[1] = dec_f;
    f1.ef = ef;         f1.gfeat = gfeat;
    f1.fmt = fmask_t;
    f1.wpack[0] = wpv;  f1.wpack[1] = wpf;
    f1.b1[0] = vM1b;    f1.b1[1] = fM1b;
    f1.b2[0] = vM2b;    f1.b2[1] = fM2b;
    f1.idx[0] = var_idx; f1.idx[1] = fun_idx;
    f1.h2[0] = hv2;     f1.h2[1] = hf2;
    f1.ns[0] = nsv;     f1.ns[1] = nsf;
    k_fused1<<<dim3(E_N / 16, 2), 256, 0, stream>>>(f1);

    F2Args f2;
    f2.wpack[0] = wpv;  f2.wpack[1] = wpf;
    f2.c1[0] = vA1b;    f2.c1[1] = fA1b;
    f2.c2[0] = vA2b;    f2.c2[1] = fA2b;
    f2.h2[0] = hv2;     f2.h2[1] = hf2;
    f2.ns[0] = nsv;     f2.ns[1] = nsf;
    f2.idx[0] = var_idx; f2.idx[1] = fun_idx;
    f2.ef = ef;         f2.emask = emask;
    f2.oldst[0] = function_state;  f2.oldst[1] = variable_state;
    f2.outst[0] = out_fs;          f2.outst[1] = out_vs;
    k_fused2<<<dim3(E_N / 16, 2), 256, 0, stream>>>(f2);
}

// Round 6
// 52.893 us; speedup vs baseline: 1.2874x; 1.2874x over previous
//
#include <hip/hip_runtime.h>

#define E_N 8192
#define V_N 2048
#define F_N 2048
#define B_N 8
#define H_N 128
#define DEC_N 128
#define EDGE_N 2
#define META_N 4
#define IN_DIM 134
#define MEMH 256
#define MEMAGG 128
#define AGGH 128

typedef __attribute__((ext_vector_type(8))) short short8;
typedef __attribute__((ext_vector_type(4))) float f32x4;

__device__ inline unsigned short f2bf(float x) {
    unsigned u = __float_as_uint(x);
    unsigned r = (u + 0x7FFFu + ((u >> 16) & 1u)) >> 16;
    return (unsigned short)r;
}

__device__ inline short8 pack8(float4 u0, float4 u1) {
    short8 s;
    s[0] = (short)f2bf(u0.x); s[1] = (short)f2bf(u0.y);
    s[2] = (short)f2bf(u0.z); s[3] = (short)f2bf(u0.w);
    s[4] = (short)f2bf(u1.x); s[5] = (short)f2bf(u1.y);
    s[6] = (short)f2bf(u1.z); s[7] = (short)f2bf(u1.w);
    return s;
}

__device__ inline int probe4(float4 v, int c, int hit) {
    if (hit < 0) {
        if      (v.x != 0.f) hit = c;
        else if (v.y != 0.f) hit = c + 1;
        else if (v.z != 0.f) hit = c + 2;
        else if (v.w != 0.f) hit = c + 3;
    }
    return hit;
}

// Scan one one-hot row (2048 floats) with chunk-512 early exit.
__device__ inline int scan_row(const float4* rp, int lane) {
    float4 a0 = rp[lane], a1 = rp[64 + lane];
    int hit = probe4(a0, lane * 4, -1);
    hit = probe4(a1, (64 + lane) * 4, hit);
    unsigned long long bm = __ballot(hit >= 0);
    for (int base = 128; base < 512 && !bm; base += 128) {
        float4 v0 = rp[base + lane], v1 = rp[base + 64 + lane];
        hit = probe4(v0, (base + lane) * 4, hit);
        hit = probe4(v1, (base + 64 + lane) * 4, hit);
        bm = __ballot(hit >= 0);
    }
    return __shfl(hit, __ffsll((long long)bm) - 1);
}

// ---------------------------------------------------------------------------
// k_prep: ONE launch doing (a) both incidence-mask scans -> vidx/fidx +
// emask/gfeat (batch id computed inline from bvm, no bov buffer), (b) zeroing
// the node-sum buffers, (c) repacking the 8 weight matrices into MFMA
// B-fragment order (bf16, K zero-padded to Kp).
// Grid layout: [0,2048) scan | [2048,2560) zero | [2560,3424) repack.
struct RDesc { const float* src; unsigned short* dst; int K; int N; int Kp; };
struct PrepArgs {
    const float* vmt; const float* fmt;
    int* vidx; int* fidx;
    const float* bvm; const int* active; const float* meta;
    float* emask; float* gfeat;
    float* nszero;
    RDesc d[8];
};
__constant__ const int RP_CUM[9] = {0, 160, 288, 368, 432, 592, 720, 800, 864};

__global__ __launch_bounds__(256) void k_prep(PrepArgs P) {
    int bid = blockIdx.x, tid = threadIdx.x;
    if (bid < 2048) {
        int wave = bid * 4 + (tid >> 6);    // 0..8191, 2 rows each
        int lane = tid & 63;
        int r0 = wave * 2;                  // combined row (even)
        bool isVar = r0 < E_N;
        const float* m = isVar ? P.vmt : P.fmt;
        int* out = isVar ? P.vidx : P.fidx;
        int e0 = isVar ? r0 : r0 - E_N;
        const float4* rpA = (const float4*)(m + (size_t)e0 * V_N);
        const float4* rpB = (const float4*)(m + (size_t)(e0 + 1) * V_N);
        int posA = scan_row(rpA, lane);
        int posB = scan_row(rpB, lane);
        if (lane < 2) {
            int pos = (lane == 0) ? posA : posB;
            int e = e0 + lane;
            out[e] = pos;
            if (isVar) {
                const float4* bv = (const float4*)(P.bvm + pos * 8);
                float4 x0 = bv[0], x1 = bv[1];
                float s = x0.y + 2.f * x0.z + 3.f * x0.w +
                          4.f * x1.x + 5.f * x1.y + 6.f * x1.z + 7.f * x1.w;
                int b = (int)(s + 0.5f);
                P.emask[e] = (float)P.active[b];
                ((float4*)P.gfeat)[e] = ((const float4*)P.meta)[b];
            }
        }
        return;
    }
    if (bid < 2560) {                       // zero node sums: 512*256 float4 = 2MB
        int gid = (bid - 2048) * 256 + tid;
        ((float4*)P.nszero)[gid] = (float4){0.f, 0.f, 0.f, 0.f};
        return;
    }
    int rb = bid - 2560;                    // repack: 864 blocks
    int mi = 0;
#pragma unroll
    for (int t = 1; t < 8; ++t) if (rb >= RP_CUM[t]) mi = t;
    RDesc d = P.d[mi];
    int i = (rb - RP_CUM[mi]) * 256 + tid;
    if (i >= d.Kp * d.N) return;
    int elem = i & 7;
    int lane = (i >> 3) & 63;
    int f    = i >> 9;
    int c16n = d.N >> 4;
    int c16 = f % c16n, kc = f / c16n;
    int k = kc * 32 + (lane >> 4) * 8 + elem;
    int c = c16 * 16 + (lane & 15);
    float v = (k < d.K) ? d.src[(size_t)k * d.N + c] : 0.f;
    d.dst[i] = f2bf(v);
}

// ---------------------------------------------------------------------------
// Fused MLP1+MLP2 per edge via MFMA, 16 edges/block (4 waves), grid 512x2.
struct F1Args {
    const float* dec[2];
    const float* ef;
    const float* gfeat;
    const unsigned short* wpack[2];
    const float* b1[2];
    const float* b2[2];
    const int* idx[2];
    float* h2[2];
    float* ns[2];
};

__global__ __launch_bounds__(256) void k_fused1(F1Args A) {
    int br = blockIdx.y;
    const float* dec = A.dec[br];
    const unsigned short* W1f = A.wpack[br];
    const unsigned short* W2f = A.wpack[br] + 160 * 256;
    const float* b1 = A.b1[br];
    const float* b2 = A.b2[br];
    const int* idx = A.idx[br];
    float* h2o = A.h2[br];
    float* ns  = A.ns[br];

    int tid = threadIdx.x;
    int wave = tid >> 6, lane = tid & 63;
    int lrow = lane & 15, lgrp = lane >> 4;
    int e0 = blockIdx.x * 16;

    __shared__ unsigned short h1s[16 * 256];  // 8 KB

    // ---- GEMM1: (16 x 256) = dvs(16 x 160pad) @ W1; wave owns 64 cols
    int n0 = wave * 64;
    f32x4 acc1[4];
#pragma unroll
    for (int nt = 0; nt < 4; ++nt) {
        float bv = b1[n0 + nt * 16 + lrow];
        acc1[nt] = (f32x4){bv, bv, bv, bv};
    }
    const float4* dec4 = (const float4*)dec;
    int r = e0 + lrow;
#pragma unroll
    for (int kc = 0; kc < 5; ++kc) {
        short8 a;
        if (kc < 4) {
            float4 u0 = dec4[(size_t)r * 32 + kc * 8 + lgrp * 2];
            float4 u1 = dec4[(size_t)r * 32 + kc * 8 + lgrp * 2 + 1];
            a = pack8(u0, u1);
        } else {
            short8 z = (short8)0;
            if (lgrp == 0) {
                z[0] = (short)f2bf(A.ef[r * 2]);
                z[1] = (short)f2bf(A.ef[r * 2 + 1]);
                z[2] = (short)f2bf(A.gfeat[r * 4]);
                z[3] = (short)f2bf(A.gfeat[r * 4 + 1]);
                z[4] = (short)f2bf(A.gfeat[r * 4 + 2]);
                z[5] = (short)f2bf(A.gfeat[r * 4 + 3]);
            }
            a = z;
        }
#pragma unroll
        for (int nt = 0; nt < 4; ++nt) {
            short8 b = *(const short8*)(W1f + ((size_t)(kc * 16 + (n0 >> 4) + nt) * 64 + lane) * 8);
            acc1[nt] = __builtin_amdgcn_mfma_f32_16x16x32_bf16(a, b, acc1[nt], 0, 0, 0);
        }
    }
    // relu -> LDS (bf16, XOR-swizzled)
#pragma unroll
    for (int nt = 0; nt < 4; ++nt)
#pragma unroll
        for (int j = 0; j < 4; ++j) {
            int row = lgrp * 4 + j;
            int col = n0 + nt * 16 + lrow;
            h1s[row * 256 + (col ^ ((row & 7) << 3))] = f2bf(fmaxf(acc1[nt][j], 0.f));
        }
    __syncthreads();

    // ---- GEMM2: (16 x 128) = h1 @ W2; wave owns 32 cols
    int c0 = wave * 32;
    f32x4 acc2[2];
#pragma unroll
    for (int nt = 0; nt < 2; ++nt) {
        float bv = b2[c0 + nt * 16 + lrow];
        acc2[nt] = (f32x4){bv, bv, bv, bv};
    }
#pragma unroll
    for (int kc = 0; kc < 8; ++kc) {
        int kb = kc * 32 + lgrp * 8;
        short8 a2 = *(const short8*)(h1s + lrow * 256 + (kb ^ ((lrow & 7) << 3)));
#pragma unroll
        for (int nt = 0; nt < 2; ++nt) {
            short8 b = *(const short8*)(W2f + ((size_t)(kc * 8 + (c0 >> 4) + nt) * 64 + lane) * 8);
            acc2[nt] = __builtin_amdgcn_mfma_f32_16x16x32_bf16(a2, b, acc2[nt], 0, 0, 0);
        }
    }
    // h2 -> global; scatter-add into node sums
#pragma unroll
    for (int j = 0; j < 4; ++j) {
        int row = e0 + lgrp * 4 + j;
        int node = idx[row];
#pragma unroll
        for (int nt = 0; nt < 2; ++nt) {
            int col = c0 + nt * 16 + lrow;
            float v = acc2[nt][j];
            h2o[(size_t)row * 128 + col] = v;
            atomicAdd(ns + (size_t)node * 128 + col, v);
        }
    }
}

// ---------------------------------------------------------------------------
struct F2Args {
    const unsigned short* wpack[2];
    const float* c1[2];
    const float* c2[2];
    const float* h2[2];
    const float* ns[2];
    const int* idx[2];
    const float* ef;
    const float* emask;
    const float* oldst[2];
    float* outst[2];
};

__global__ __launch_bounds__(256) void k_fused2(F2Args A) {
    int br = blockIdx.y;
    const unsigned short* A1f = A.wpack[br] + 160 * 256 + 256 * 128;
    const unsigned short* A2f = A1f + 160 * 128;
    const float* c1 = A.c1[br];
    const float* c2 = A.c2[br];
    const float* h2 = A.h2[br];
    const float* ns = A.ns[br];
    const int* idx = A.idx[br];
    const float* oldst = A.oldst[br];
    float* outst = A.outst[br];

    int tid = threadIdx.x;
    int wave = tid >> 6, lane = tid & 63;
    int lrow = lane & 15, lgrp = lane >> 4;
    int e0 = blockIdx.x * 16;

    __shared__ unsigned short as_[16 * 128];  // 4 KB

    int n0 = wave * 32;
    f32x4 accp[2];
#pragma unroll
    for (int nt = 0; nt < 2; ++nt) {
        float bv = c1[n0 + nt * 16 + lrow];
        accp[nt] = (f32x4){bv, bv, bv, bv};
    }
    const float4* ns4 = (const float4*)ns;
    const float4* h24 = (const float4*)h2;
    int r = e0 + lrow;
    int node = idx[r];
#pragma unroll
    for (int kc = 0; kc < 5; ++kc) {
        short8 a;
        if (kc < 4) {
            float4 u0 = ns4[(size_t)node * 32 + kc * 8 + lgrp * 2];
            float4 u1 = ns4[(size_t)node * 32 + kc * 8 + lgrp * 2 + 1];
            float4 v0 = h24[(size_t)r * 32 + kc * 8 + lgrp * 2];
            float4 v1 = h24[(size_t)r * 32 + kc * 8 + lgrp * 2 + 1];
            float4 d0 = {u0.x - v0.x, u0.y - v0.y, u0.z - v0.z, u0.w - v0.w};
            float4 d1 = {u1.x - v1.x, u1.y - v1.y, u1.z - v1.z, u1.w - v1.w};
            a = pack8(d0, d1);
        } else {
            short8 z = (short8)0;
            if (lgrp == 0) {
                z[0] = (short)f2bf(A.ef[r * 2]);
                z[1] = (short)f2bf(A.ef[r * 2 + 1]);
            }
            a = z;
        }
#pragma unroll
        for (int nt = 0; nt < 2; ++nt) {
            short8 b = *(const short8*)(A1f + ((size_t)(kc * 8 + (n0 >> 4) + nt) * 64 + lane) * 8);
            accp[nt] = __builtin_amdgcn_mfma_f32_16x16x32_bf16(a, b, accp[nt], 0, 0, 0);
        }
    }
#pragma unroll
    for (int nt = 0; nt < 2; ++nt)
#pragma unroll
        for (int j = 0; j < 4; ++j) {
            int row = lgrp * 4 + j;
            int col = n0 + nt * 16 + lrow;
            as_[row * 128 + (col ^ ((row & 7) << 3))] = f2bf(fmaxf(accp[nt][j], 0.f));
        }
    __syncthreads();

    f32x4 acco[2];
#pragma unroll
    for (int nt = 0; nt < 2; ++nt) {
        float bv = c2[n0 + nt * 16 + lrow];
        acco[nt] = (f32x4){bv, bv, bv, bv};
    }
#pragma unroll
    for (int kc = 0; kc < 4; ++kc) {
        int kb = kc * 32 + lgrp * 8;
        short8 a2 = *(const short8*)(as_ + lrow * 128 + (kb ^ ((lrow & 7) << 3)));
#pragma unroll
        for (int nt = 0; nt < 2; ++nt) {
            short8 b = *(const short8*)(A2f + ((size_t)(kc * 8 + (n0 >> 4) + nt) * 64 + lane) * 8);
            acco[nt] = __builtin_amdgcn_mfma_f32_16x16x32_bf16(a2, b, acco[nt], 0, 0, 0);
        }
    }
#pragma unroll
    for (int j = 0; j < 4; ++j) {
        int row = e0 + lgrp * 4 + j;
        float m = A.emask[row];
#pragma unroll
        for (int nt = 0; nt < 2; ++nt) {
            int col = n0 + nt * 16 + lrow;
            float old = oldst[(size_t)row * 128 + col];
            outst[(size_t)row * 128 + col] = m * acco[nt][j] + (1.f - m) * old;
        }
    }
}

// ---------------------------------------------------------------------------
extern "C" void kernel_launch(void* const* d_in, const int* in_sizes, int n_in,
                              void* d_out, int out_size, void* d_ws, size_t ws_size,
                              hipStream_t stream) {
    const float* variable_state = (const float*)d_in[0];
    const float* function_state = (const float*)d_in[1];
    const float* dec_v          = (const float*)d_in[2];
    const float* dec_f          = (const float*)d_in[3];
    const float* ef             = (const float*)d_in[4];
    const float* meta           = (const float*)d_in[5];
    const int*   active         = (const int*)d_in[6];
    const float* vmask_t        = (const float*)d_in[8];
    const float* fmask_t        = (const float*)d_in[10];
    const float* bvm            = (const float*)d_in[11];
    const float* vM1w = (const float*)d_in[12]; const float* vM1b = (const float*)d_in[13];
    const float* vM2w = (const float*)d_in[14]; const float* vM2b = (const float*)d_in[15];
    const float* vA1w = (const float*)d_in[16]; const float* vA1b = (const float*)d_in[17];
    const float* vA2w = (const float*)d_in[18]; const float* vA2b = (const float*)d_in[19];
    const float* fM1w = (const float*)d_in[20]; const float* fM1b = (const float*)d_in[21];
    const float* fM2w = (const float*)d_in[22]; const float* fM2b = (const float*)d_in[23];
    const float* fA1w = (const float*)d_in[24]; const float* fA1b = (const float*)d_in[25];
    const float* fA2w = (const float*)d_in[26]; const float* fA2b = (const float*)d_in[27];

    float* out_vs = (float*)d_out;
    float* out_fs = (float*)d_out + (size_t)E_N * H_N;

    int*   var_idx = (int*)d_ws;                        // E
    int*   fun_idx = var_idx + E_N;                     // E
    float* emask   = (float*)(fun_idx + E_N);           // E
    float* gfeat   = emask + E_N;                       // 4E
    float* hv2     = gfeat + (size_t)E_N * 4;           // 128E
    float* hf2     = hv2 + (size_t)E_N * MEMAGG;        // 128E
    float* nsv     = hf2 + (size_t)E_N * MEMAGG;        // 128V
    float* nsf     = nsv + (size_t)V_N * MEMAGG;        // 128F
    unsigned short* wpack = (unsigned short*)(nsf + (size_t)F_N * MEMAGG);
    const int PBR = 160 * 256 + 256 * 128 + 160 * 128 + 128 * 128;  // 110592
    unsigned short* wpv = wpack;
    unsigned short* wpf = wpack + PBR;

    PrepArgs pp;
    pp.vmt = vmask_t; pp.fmt = fmask_t;
    pp.vidx = var_idx; pp.fidx = fun_idx;
    pp.bvm = bvm; pp.active = active; pp.meta = meta;
    pp.emask = emask; pp.gfeat = gfeat;
    pp.nszero = nsv;
    pp.d[0] = {vM1w, wpv,                          IN_DIM, MEMH,   160};
    pp.d[1] = {vM2w, wpv + 160 * 256,              MEMH,   MEMAGG, 256};
    pp.d[2] = {vA1w, wpv + 160 * 256 + 256 * 128,  130,    AGGH,   160};
    pp.d[3] = {vA2w, wpv + 160 * 256 + 256 * 128 + 160 * 128, 128, H_N, 128};
    pp.d[4] = {fM1w, wpf,                          IN_DIM, MEMH,   160};
    pp.d[5] = {fM2w, wpf + 160 * 256,              MEMH,   MEMAGG, 256};
    pp.d[6] = {fA1w, wpf + 160 * 256 + 256 * 128,  130,    AGGH,   160};
    pp.d[7] = {fA2w, wpf + 160 * 256 + 256 * 128 + 160 * 128, 128, H_N, 128};
    k_prep<<<3424, 256, 0, stream>>>(pp);

    F1Args f1;
    f1.dec[0] = dec_v;  f1.dec[1] = dec_f;
    f1.ef = ef;         f1.gfeat = gfeat;
    f1.wpack[0] = wpv;  f1.wpack[1] = wpf;
    f1.b1[0] = vM1b;    f1.b1[1] = fM1b;
    f1.b2[0] = vM2b;    f1.b2[1] = fM2b;
    f1.idx[0] = var_idx; f1.idx[1] = fun_idx;
    f1.h2[0] = hv2;     f1.h2[1] = hf2;
    f1.ns[0] = nsv;     f1.ns[1] = nsf;
    k_fused1<<<dim3(E_N / 16, 2), 256, 0, stream>>>(f1);

    F2Args f2;
    f2.wpack[0] = wpv;  f2.wpack[1] = wpf;
    f2.c1[0] = vA1b;    f2.c1[1] = fA1b;
    f2.c2[0] = vA2b;    f2.c2[1] = fA2b;
    f2.h2[0] = hv2;     f2.h2[1] = hf2;
    f2.ns[0] = nsv;     f2.ns[1] = nsf;
    f2.idx[0] = var_idx; f2.idx[1] = fun_idx;
    f2.ef = ef;         f2.emask = emask;
    f2.oldst[0] = function_state;  f2.oldst[1] = variable_state;
    f2.outst[0] = out_fs;          f2.outst[1] = out_vs;
    k_fused2<<<dim3(E_N / 16, 2), 256, 0, stream>>>(f2);
}